// Round 3
// baseline (246.470 us; speedup 1.0000x reference)
//
#include <hip/hip_runtime.h>
#include <hip/hip_bf16.h>

#define B_N    16
#define C_IN   64
#define QDIM   576
#define OC     128
#define M_TOT  36864
#define NKT    81
#define PLANE  2512   // 50*50 = 2500 padded to multiple of 8 for 16B stores

typedef __attribute__((ext_vector_type(8))) short short8;
typedef __attribute__((ext_vector_type(4))) float floatx4;

__device__ __forceinline__ unsigned short f2bf(float f) {
    union { float f; unsigned u; } v; v.f = f;
    unsigned r = (v.u + 0x7FFFu + ((v.u >> 16) & 1u)) >> 16;
    return (unsigned short)r;
}

// phi[0] = silu(x); phi[1..8] = cubic B-spline bases on uniform grid [-2.2..2.2], h=0.4.
// Uniform grid -> Cox-de Boor denominators are k*h; exact reciprocal constants.
__device__ __forceinline__ void compute_phi(float x, float* phi) {
    phi[0] = x * __builtin_amdgcn_rcpf(1.0f + __expf(-x));
    float t[12];
#pragma unroll
    for (int i = 0; i < 12; ++i) t[i] = 0.4f * (float)(i - 3) - 1.0f;
    float bb[11];
#pragma unroll
    for (int j = 0; j < 11; ++j) bb[j] = (x >= t[j] && x < t[j + 1]) ? 1.0f : 0.0f;
#pragma unroll
    for (int j = 0; j < 10; ++j)
        bb[j] = (x - t[j]) * 2.5f * bb[j] + (t[j + 2] - x) * 2.5f * bb[j + 1];
#pragma unroll
    for (int j = 0; j < 9; ++j)
        bb[j] = (x - t[j]) * 1.25f * bb[j] + (t[j + 3] - x) * 1.25f * bb[j + 1];
#pragma unroll
    for (int j = 0; j < 8; ++j)
        bb[j] = (x - t[j]) * (2.5f / 3.0f) * bb[j] + (t[j + 4] - x) * (2.5f / 3.0f) * bb[j + 1];
#pragma unroll
    for (int g = 0; g < 8; ++g) phi[1 + g] = bb[g];
}

// Pass 1: Phi[b][c][j][2512], padded 50x50 plane. 8 pixels/thread, short8 stores.
__global__ __launch_bounds__(256) void phi_kernel(const float* __restrict__ x,
                                                  unsigned short* __restrict__ Phi) {
    int ch = blockIdx.x * 256 + threadIdx.x;   // 1024 bc * 314 chunks
    int bc = ch / 314;
    int cp = ch - bc * 314;
    int p0 = cp * 8;
    const float* xsrc = x + (size_t)bc * 2304;
    short8 v[9];
#pragma unroll
    for (int e = 0; e < 8; ++e) {
        int p = p0 + e;
        int hh = p / 50;
        int ww = p - hh * 50;
        float xv = (hh >= 1 && hh <= 48 && ww >= 1 && ww <= 48) ? xsrc[(hh - 1) * 48 + (ww - 1)] : 0.0f;
        float phi[9];
        compute_phi(xv, phi);
#pragma unroll
        for (int j = 0; j < 9; ++j) v[j][e] = (short)f2bf(phi[j]);
    }
    unsigned short* pdst = Phi + (size_t)bc * 9 * PLANE + p0;
#pragma unroll
    for (int j = 0; j < 9; ++j) *(short8*)(pdst + (size_t)j * PLANE) = v[j];
}

// Pass 0: pack weights in MFMA-fragment-contiguous order.
// Tile kt (16KB): [f=oc/16 : 8][ks=(k&63)>>5 : 2][lane=((k&31)>>3)*16 + (oc&15) : 64][e=k&7 : 8] bf16.
// Each lane's B-fragment (oc = f*16+(lane&15), k-run of 8) is one contiguous 16B.
__global__ __launch_bounds__(256) void pack_kernel(const float* __restrict__ bw,
                                                   const float* __restrict__ sw,
                                                   const float* __restrict__ sc,
                                                   unsigned short* __restrict__ Wp) {
    int gtid = blockIdx.x * 256 + threadIdx.x;  // oc*576 + q ; 73728 total
    int oc = gtid / QDIM, q = gtid % QDIM;
    float base = bw[gtid];
    float scal = sc[gtid];
    unsigned char* wp8 = (unsigned char*)Wp;
    int kk = q & 63;
    int inner = (oc >> 4) * 2048 + (kk >> 5) * 1024
              + ((((kk >> 3) & 3) << 4) + (oc & 15)) * 16 + (kk & 7) * 2;
    int ktb = q >> 6;
    *(unsigned short*)(wp8 + (size_t)ktb * 16384 + inner) = f2bf(base);
#pragma unroll
    for (int g = 0; g < 8; ++g) {
        float v = sw[(size_t)gtid * 8 + g] * scal;
        *(unsigned short*)(wp8 + (size_t)((g + 1) * 9 + ktb) * 16384 + inner) = f2bf(v);
    }
}

// GEMM: out[n][oc] = sum_k A[n][k]*W[k][oc].  M=36864, N=128, K=5184.
// Tile BM=48, BN=128, BK=64; grid=768 = exactly 3 blocks/CU.
// 4 waves = (wo: oc-half) x (wk: k-half); wave tile 48m x 64oc x 32k, acc[3][4].
// A staged via global_load_lds (only 6KB/step); W loaded straight to registers from L2
// (fragment-contiguous Wp), double-buffered one K-step ahead. K-halves reduced via LDS.
__global__ __launch_bounds__(256, 4) void gemm_kernel(const unsigned short* __restrict__ Phi,
                                                      const unsigned short* __restrict__ Wp,
                                                      float* __restrict__ out) {
    __shared__ __align__(16) unsigned char lds[24960]; // A dbuf 2x6K; epilogue f32 [2][48][65]
    int bid = blockIdx.x;
    int swzb = (bid & 7) * 96 + (bid >> 3);   // XCD-bijective (768 = 8*96)
    int m0 = swzb * 48;
    int tid = threadIdx.x;
    int lane = tid & 63;
    int wv = tid >> 6;
    int wo = wv & 1, wk = wv >> 1;
    int lo = lane & 15, hi = lane >> 4, l7 = lane & 7;

    // A staging: chunks 0..255 = rows 0..31 (all tids), chunks 256..383 = rows 32..47 (tid<128)
    int s8 = tid & 7;
    int rA = tid >> 3;
    int sxA = s8 ^ (rA & 7);
    int rB = (tid < 128) ? (32 + (tid >> 3)) : rA;
    int sxB = s8 ^ (rB & 7);

    size_t rowb[2];
    int rows[2] = {rA, rB};
#pragma unroll
    for (int i = 0; i < 2; ++i) {
        int n  = m0 + rows[i];
        int b  = n / 2304;
        int u  = n - b * 2304;
        int du = u >> 2;          // patches feature (c,kh,kw)
        int r  = u & 3;           // 576-chunk within reinterpreted row
        int c  = du / 9;
        int tap = du - c * 9;
        int kh = tap / 3, kw = tap - kh * 3;
        rowb[i] = ((size_t)(b * C_IN + c) * 9) * PLANE + (size_t)((r * 12 + kh) * 50 + kw);
    }

    auto stageA = [&](int sel, int kt) {
        int j  = kt / 9;
        int q0 = (kt - j * 9) << 6;
        unsigned char* pb = lds + sel * 6144;
        {
            int qs = q0 + sxA * 8;
            int hq = qs / 48, wq = qs - hq * 48;   // 16B chunk never crosses 48-wrap
            const unsigned short* src = Phi + rowb[0] + (size_t)j * PLANE + (size_t)(hq * 50 + wq);
            __builtin_amdgcn_global_load_lds((const __attribute__((address_space(1))) void*)src,
                                             (__attribute__((address_space(3))) void*)(pb + tid * 16), 16, 0, 0);
        }
        if (tid < 128) {
            int qs = q0 + sxB * 8;
            int hq = qs / 48, wq = qs - hq * 48;
            const unsigned short* src = Phi + rowb[1] + (size_t)j * PLANE + (size_t)(hq * 50 + wq);
            __builtin_amdgcn_global_load_lds((const __attribute__((address_space(1))) void*)src,
                                             (__attribute__((address_space(3))) void*)(pb + 4096 + tid * 16), 16, 0, 0);
        }
    };

    const unsigned char* wsrc = (const unsigned char*)Wp
                              + (size_t)(wo * 4) * 2048 + (size_t)wk * 1024 + (size_t)lane * 16;
    auto loadW = [&](short8* wf, int kt) {
        const unsigned char* s = wsrc + (size_t)kt * 16384;
#pragma unroll
        for (int fo = 0; fo < 4; ++fo) wf[fo] = *(const short8*)(s + fo * 2048);
    };

    floatx4 acc[3][4];
    floatx4 zz = {0.f, 0.f, 0.f, 0.f};
#pragma unroll
    for (int a = 0; a < 3; ++a)
#pragma unroll
        for (int b = 0; b < 4; ++b) acc[a][b] = zz;

    int sxr = ((wk * 4 + hi) ^ l7) << 4;   // swizzled chunk-slot byte offset in A rows
    int arow[3];
#pragma unroll
    for (int fm = 0; fm < 3; ++fm) arow[fm] = (fm * 16 + lo) * 128;

    auto compute = [&](int sel, const short8* wf) {
        const unsigned char* pb = lds + sel * 6144;
        short8 af[3];
#pragma unroll
        for (int fm = 0; fm < 3; ++fm) af[fm] = *(const short8*)(pb + arow[fm] + sxr);
#pragma unroll
        for (int fm = 0; fm < 3; ++fm)
#pragma unroll
            for (int fo = 0; fo < 4; ++fo)
                acc[fm][fo] = __builtin_amdgcn_mfma_f32_16x16x32_bf16(af[fm], wf[fo], acc[fm][fo], 0, 0, 0);
    };

    short8 wA[4], wB[4];
    stageA(0, 0);
    loadW(wA, 0);
    __syncthreads();
    for (int kt = 0; kt < NKT; kt += 2) {
        if (kt + 1 < NKT) { stageA(1, kt + 1); loadW(wB, kt + 1); }
        compute(0, wA);
        __syncthreads();
        if (kt + 1 >= NKT) break;
        if (kt + 2 < NKT) { stageA(0, kt + 2); loadW(wA, kt + 2); }
        compute(1, wB);
        __syncthreads();
    }

    // Epilogue: reduce k-halves via LDS (f32 [2][48][65]), then store.
    float* red = (float*)lds;
    if (wk == 1) {
#pragma unroll
        for (int fm = 0; fm < 3; ++fm)
#pragma unroll
            for (int fo = 0; fo < 4; ++fo)
#pragma unroll
                for (int r = 0; r < 4; ++r)
                    red[(wo * 48 + fm * 16 + hi * 4 + r) * 65 + fo * 16 + lo] = acc[fm][fo][r];
    }
    __syncthreads();
    if (wk == 0) {
#pragma unroll
        for (int fm = 0; fm < 3; ++fm) {
#pragma unroll
            for (int fo = 0; fo < 4; ++fo) {
                int oc = wo * 64 + fo * 16 + lo;
#pragma unroll
                for (int r = 0; r < 4; ++r) {
                    int nrow = m0 + fm * 16 + hi * 4 + r;
                    out[(size_t)nrow * 128 + oc] =
                        acc[fm][fo][r] + red[(wo * 48 + fm * 16 + hi * 4 + r) * 65 + fo * 16 + lo];
                }
            }
        }
    }
}

extern "C" void kernel_launch(void* const* d_in, const int* in_sizes, int n_in,
                              void* d_out, int out_size, void* d_ws, size_t ws_size,
                              hipStream_t stream) {
    const float* x  = (const float*)d_in[0];
    const float* bw = (const float*)d_in[1];
    const float* sw = (const float*)d_in[2];
    const float* sc = (const float*)d_in[3];
    float* out = (float*)d_out;

    unsigned short* Wp  = (unsigned short*)d_ws;                        // 81*16384 = 1.33 MB
    unsigned short* Phi = (unsigned short*)((char*)d_ws + 1572864);     // 1024*9*2512*2 = 46.3 MB

    pack_kernel<<<288, 256, 0, stream>>>(bw, sw, sc, Wp);
    phi_kernel<<<1256, 256, 0, stream>>>(x, Phi);
    gemm_kernel<<<M_TOT / 48, 256, 0, stream>>>(Phi, Wp, out);
}

// Round 4
// 151.367 us; speedup vs baseline: 1.6283x; 1.6283x over previous
//
#include <hip/hip_runtime.h>
#include <hip/hip_bf16.h>

#define B_N    16
#define C_IN   64
#define QDIM   576
#define OC     128
#define M_TOT  36864
#define NKT    81
#define PLANE  2512   // 50*50 = 2500 padded to multiple of 8 for 16B stores

typedef __attribute__((ext_vector_type(8))) short short8;
typedef __attribute__((ext_vector_type(4))) float floatx4;

__device__ __forceinline__ unsigned short f2bf(float f) {
    union { float f; unsigned u; } v; v.f = f;
    unsigned r = (v.u + 0x7FFFu + ((v.u >> 16) & 1u)) >> 16;
    return (unsigned short)r;
}

// phi[0] = silu(x); phi[1..8] = cubic B-spline bases on uniform grid [-2.2..2.2], h=0.4.
__device__ __forceinline__ void compute_phi(float x, float* phi) {
    phi[0] = x * __builtin_amdgcn_rcpf(1.0f + __expf(-x));
    float t[12];
#pragma unroll
    for (int i = 0; i < 12; ++i) t[i] = 0.4f * (float)(i - 3) - 1.0f;
    float bb[11];
#pragma unroll
    for (int j = 0; j < 11; ++j) bb[j] = (x >= t[j] && x < t[j + 1]) ? 1.0f : 0.0f;
#pragma unroll
    for (int j = 0; j < 10; ++j)
        bb[j] = (x - t[j]) * 2.5f * bb[j] + (t[j + 2] - x) * 2.5f * bb[j + 1];
#pragma unroll
    for (int j = 0; j < 9; ++j)
        bb[j] = (x - t[j]) * 1.25f * bb[j] + (t[j + 3] - x) * 1.25f * bb[j + 1];
#pragma unroll
    for (int j = 0; j < 8; ++j)
        bb[j] = (x - t[j]) * (2.5f / 3.0f) * bb[j] + (t[j + 4] - x) * (2.5f / 3.0f) * bb[j + 1];
#pragma unroll
    for (int g = 0; g < 8; ++g) phi[1 + g] = bb[g];
}

// Pass 1: Phi[b][c][j][2512], padded 50x50 plane. 8 pixels/thread, short8 stores.
__global__ __launch_bounds__(256) void phi_kernel(const float* __restrict__ x,
                                                  unsigned short* __restrict__ Phi) {
    int ch = blockIdx.x * 256 + threadIdx.x;   // 1024 bc * 314 chunks
    int bc = ch / 314;
    int cp = ch - bc * 314;
    int p0 = cp * 8;
    const float* xsrc = x + (size_t)bc * 2304;
    short8 v[9];
#pragma unroll
    for (int e = 0; e < 8; ++e) {
        int p = p0 + e;
        int hh = p / 50;
        int ww = p - hh * 50;
        float xv = (hh >= 1 && hh <= 48 && ww >= 1 && ww <= 48) ? xsrc[(hh - 1) * 48 + (ww - 1)] : 0.0f;
        float phi[9];
        compute_phi(xv, phi);
#pragma unroll
        for (int j = 0; j < 9; ++j) v[j][e] = (short)f2bf(phi[j]);
    }
    unsigned short* pdst = Phi + (size_t)bc * 9 * PLANE + p0;
#pragma unroll
    for (int j = 0; j < 9; ++j) *(short8*)(pdst + (size_t)j * PLANE) = v[j];
}

// Pass 0: pack weights in MFMA-fragment-contiguous order.
// Tile kt (16KB): [f=oc/16][ks=(k&63)>>5][lane=hi*16+lo][e=k&7] bf16; each lane's
// B-fragment (8 consecutive k for one oc) is one contiguous 16B.
__global__ __launch_bounds__(256) void pack_kernel(const float* __restrict__ bw,
                                                   const float* __restrict__ sw,
                                                   const float* __restrict__ sc,
                                                   unsigned short* __restrict__ Wp) {
    int gtid = blockIdx.x * 256 + threadIdx.x;  // oc*576 + q ; 73728 total
    int oc = gtid / QDIM, q = gtid % QDIM;
    float base = bw[gtid];
    float scal = sc[gtid];
    unsigned char* wp8 = (unsigned char*)Wp;
    int kk = q & 63;
    int inner = (oc >> 4) * 2048 + (kk >> 5) * 1024
              + ((((kk >> 3) & 3) << 4) + (oc & 15)) * 16 + (kk & 7) * 2;
    int ktb = q >> 6;
    *(unsigned short*)(wp8 + (size_t)ktb * 16384 + inner) = f2bf(base);
#pragma unroll
    for (int g = 0; g < 8; ++g) {
        float v = sw[(size_t)gtid * 8 + g] * scal;
        *(unsigned short*)(wp8 + (size_t)((g + 1) * 9 + ktb) * 16384 + inner) = f2bf(v);
    }
}

#define MFMA_BF16 __builtin_amdgcn_mfma_f32_16x16x32_bf16

// GEMM: out[n][oc] = sum_k A[n][k]*W[k][oc].  M=36864, N=128, K=5184.
// Tile BM=48, BN=128, BK=64; grid=768 = exactly 3 blocks/CU.
// 4 waves = (wo: oc-half) x (wk: k-half); wave tile 48m x 64oc x 32k, acc[3][4].
// A staged via global_load_lds (6KB/step, dbuf); W loaded straight to NAMED registers
// from L2 (fragment-contiguous Wp), double-buffered. K-halves reduced via LDS epilogue.
__global__ __launch_bounds__(256, 3) void gemm_kernel(const unsigned short* __restrict__ Phi,
                                                      const unsigned short* __restrict__ Wp,
                                                      float* __restrict__ out) {
    __shared__ __align__(16) unsigned char lds[24960]; // A dbuf 2x6K; epilogue f32 [2][48][65]
    int bid = blockIdx.x;
    int swzb = (bid & 7) * 96 + (bid >> 3);   // XCD-bijective (768 = 8*96)
    int m0 = swzb * 48;
    int tid = threadIdx.x;
    int lane = tid & 63;
    int wv = tid >> 6;
    int wo = wv & 1, wk = wv >> 1;
    int lo = lane & 15, hi = lane >> 4, l7 = lane & 7;

    // A staging: chunks 0..255 = rows 0..31 (all tids), chunks 256..383 = rows 32..47 (tid<128)
    int s8 = tid & 7;
    int rA = tid >> 3;
    int sxA = s8 ^ (rA & 7);
    int rB = (tid < 128) ? (32 + (tid >> 3)) : rA;
    int sxB = s8 ^ (rB & 7);

    size_t rowb[2];
    int rows[2] = {rA, rB};
#pragma unroll
    for (int i = 0; i < 2; ++i) {
        int n  = m0 + rows[i];
        int b  = n / 2304;
        int u  = n - b * 2304;
        int du = u >> 2;          // patches feature (c,kh,kw)
        int r  = u & 3;           // 576-chunk within reinterpreted row
        int c  = du / 9;
        int tap = du - c * 9;
        int kh = tap / 3, kw = tap - kh * 3;
        rowb[i] = ((size_t)(b * C_IN + c) * 9) * PLANE + (size_t)((r * 12 + kh) * 50 + kw);
    }

    auto stageA = [&](int sel, int kt) {
        int j  = kt / 9;
        int q0 = (kt - j * 9) << 6;
        unsigned char* pb = lds + sel * 6144;
        {
            int qs = q0 + sxA * 8;
            int hq = qs / 48, wq = qs - hq * 48;   // 16B chunk never crosses 48-wrap
            const unsigned short* src = Phi + rowb[0] + (size_t)j * PLANE + (size_t)(hq * 50 + wq);
            __builtin_amdgcn_global_load_lds((const __attribute__((address_space(1))) void*)src,
                                             (__attribute__((address_space(3))) void*)(pb + tid * 16), 16, 0, 0);
        }
        if (tid < 128) {
            int qs = q0 + sxB * 8;
            int hq = qs / 48, wq = qs - hq * 48;
            const unsigned short* src = Phi + rowb[1] + (size_t)j * PLANE + (size_t)(hq * 50 + wq);
            __builtin_amdgcn_global_load_lds((const __attribute__((address_space(1))) void*)src,
                                             (__attribute__((address_space(3))) void*)(pb + 4096 + tid * 16), 16, 0, 0);
        }
    };

    const unsigned char* wsrc = (const unsigned char*)Wp
                              + (size_t)wo * 8192 + (size_t)wk * 1024 + (size_t)lane * 16;

#define LOADW(W0, W1, W2, W3, KT) do {                                      \
        const unsigned char* s_ = wsrc + (size_t)(KT) * 16384;              \
        W0 = *(const short8*)(s_);                                          \
        W1 = *(const short8*)(s_ + 2048);                                   \
        W2 = *(const short8*)(s_ + 4096);                                   \
        W3 = *(const short8*)(s_ + 6144);                                   \
    } while (0)

#define COMPUTE(SEL, W0, W1, W2, W3) do {                                   \
        const unsigned char* pb_ = lds + (SEL) * 6144;                      \
        short8 a0_ = *(const short8*)(pb_ + arow0 + sxr);                   \
        short8 a1_ = *(const short8*)(pb_ + arow1 + sxr);                   \
        short8 a2_ = *(const short8*)(pb_ + arow2 + sxr);                   \
        acc[0][0] = MFMA_BF16(a0_, W0, acc[0][0], 0, 0, 0);                 \
        acc[0][1] = MFMA_BF16(a0_, W1, acc[0][1], 0, 0, 0);                 \
        acc[0][2] = MFMA_BF16(a0_, W2, acc[0][2], 0, 0, 0);                 \
        acc[0][3] = MFMA_BF16(a0_, W3, acc[0][3], 0, 0, 0);                 \
        acc[1][0] = MFMA_BF16(a1_, W0, acc[1][0], 0, 0, 0);                 \
        acc[1][1] = MFMA_BF16(a1_, W1, acc[1][1], 0, 0, 0);                 \
        acc[1][2] = MFMA_BF16(a1_, W2, acc[1][2], 0, 0, 0);                 \
        acc[1][3] = MFMA_BF16(a1_, W3, acc[1][3], 0, 0, 0);                 \
        acc[2][0] = MFMA_BF16(a2_, W0, acc[2][0], 0, 0, 0);                 \
        acc[2][1] = MFMA_BF16(a2_, W1, acc[2][1], 0, 0, 0);                 \
        acc[2][2] = MFMA_BF16(a2_, W2, acc[2][2], 0, 0, 0);                 \
        acc[2][3] = MFMA_BF16(a2_, W3, acc[2][3], 0, 0, 0);                 \
    } while (0)

    floatx4 acc[3][4];
    floatx4 zz = {0.f, 0.f, 0.f, 0.f};
#pragma unroll
    for (int a = 0; a < 3; ++a)
#pragma unroll
        for (int b = 0; b < 4; ++b) acc[a][b] = zz;

    int sxr = ((wk * 4 + hi) ^ l7) << 4;   // swizzled chunk-slot byte offset in A rows
    int arow0 = (0 * 16 + lo) * 128;
    int arow1 = (1 * 16 + lo) * 128;
    int arow2 = (2 * 16 + lo) * 128;

    short8 u0, u1, u2, u3, v0, v1, v2, v3;
    stageA(0, 0);
    LOADW(u0, u1, u2, u3, 0);
    __syncthreads();
    for (int kt = 0; kt < NKT - 1; kt += 2) {
        stageA(1, kt + 1);
        LOADW(v0, v1, v2, v3, kt + 1);
        COMPUTE(0, u0, u1, u2, u3);
        __syncthreads();
        if (kt + 2 < NKT) {
            stageA(0, kt + 2);
            LOADW(u0, u1, u2, u3, kt + 2);
        }
        COMPUTE(1, v0, v1, v2, v3);
        __syncthreads();
    }
    COMPUTE(0, u0, u1, u2, u3);   // kt = 80 (staged/loaded in final iteration)
    __syncthreads();

    // Epilogue: reduce k-halves via LDS (f32 [2][48][65]), then store.
    float* red = (float*)lds;
    if (wk == 1) {
#pragma unroll
        for (int fm = 0; fm < 3; ++fm)
#pragma unroll
            for (int fo = 0; fo < 4; ++fo)
#pragma unroll
                for (int r = 0; r < 4; ++r)
                    red[(wo * 48 + fm * 16 + hi * 4 + r) * 65 + fo * 16 + lo] = acc[fm][fo][r];
    }
    __syncthreads();
    if (wk == 0) {
#pragma unroll
        for (int fm = 0; fm < 3; ++fm) {
#pragma unroll
            for (int fo = 0; fo < 4; ++fo) {
                int oc = wo * 64 + fo * 16 + lo;
#pragma unroll
                for (int r = 0; r < 4; ++r) {
                    int nrow = m0 + fm * 16 + hi * 4 + r;
                    out[(size_t)nrow * 128 + oc] =
                        acc[fm][fo][r] + red[(wo * 48 + fm * 16 + hi * 4 + r) * 65 + fo * 16 + lo];
                }
            }
        }
    }
#undef LOADW
#undef COMPUTE
}

extern "C" void kernel_launch(void* const* d_in, const int* in_sizes, int n_in,
                              void* d_out, int out_size, void* d_ws, size_t ws_size,
                              hipStream_t stream) {
    const float* x  = (const float*)d_in[0];
    const float* bw = (const float*)d_in[1];
    const float* sw = (const float*)d_in[2];
    const float* sc = (const float*)d_in[3];
    float* out = (float*)d_out;

    unsigned short* Wp  = (unsigned short*)d_ws;                        // 81*16384 = 1.33 MB
    unsigned short* Phi = (unsigned short*)((char*)d_ws + 1572864);     // 1024*9*2512*2 = 46.3 MB

    pack_kernel<<<288, 256, 0, stream>>>(bw, sw, sc, Wp);
    phi_kernel<<<1256, 256, 0, stream>>>(x, Phi);
    gemm_kernel<<<M_TOT / 48, 256, 0, stream>>>(Phi, Wp, out);
}

// Round 5
// 149.926 us; speedup vs baseline: 1.6439x; 1.0096x over previous
//
#include <hip/hip_runtime.h>
#include <hip/hip_bf16.h>

#define B_N    16
#define C_IN   64
#define QDIM   576
#define OC     128
#define M_TOT  36864
#define NKT    81
#define PLANE  2512   // 50*50 = 2500 padded to multiple of 8 for 16B stores

typedef __attribute__((ext_vector_type(8))) short short8;
typedef __attribute__((ext_vector_type(4))) float floatx4;

__device__ __forceinline__ unsigned short f2bf(float f) {
    union { float f; unsigned u; } v; v.f = f;
    unsigned r = (v.u + 0x7FFFu + ((v.u >> 16) & 1u)) >> 16;
    return (unsigned short)r;
}

// phi[0] = silu(x); phi[1..8] = cubic B-spline bases on uniform grid [-2.2..2.2], h=0.4.
__device__ __forceinline__ void compute_phi(float x, float* phi) {
    phi[0] = x * __builtin_amdgcn_rcpf(1.0f + __expf(-x));
    float t[12];
#pragma unroll
    for (int i = 0; i < 12; ++i) t[i] = 0.4f * (float)(i - 3) - 1.0f;
    float bb[11];
#pragma unroll
    for (int j = 0; j < 11; ++j) bb[j] = (x >= t[j] && x < t[j + 1]) ? 1.0f : 0.0f;
#pragma unroll
    for (int j = 0; j < 10; ++j)
        bb[j] = (x - t[j]) * 2.5f * bb[j] + (t[j + 2] - x) * 2.5f * bb[j + 1];
#pragma unroll
    for (int j = 0; j < 9; ++j)
        bb[j] = (x - t[j]) * 1.25f * bb[j] + (t[j + 3] - x) * 1.25f * bb[j + 1];
#pragma unroll
    for (int j = 0; j < 8; ++j)
        bb[j] = (x - t[j]) * (2.5f / 3.0f) * bb[j] + (t[j + 4] - x) * (2.5f / 3.0f) * bb[j + 1];
#pragma unroll
    for (int g = 0; g < 8; ++g) phi[1 + g] = bb[g];
}

// Pass 1: Phi[b][c][j][2512], padded 50x50 plane. 8 pixels/thread, short8 stores.
__global__ __launch_bounds__(256) void phi_kernel(const float* __restrict__ x,
                                                  unsigned short* __restrict__ Phi) {
    int ch = blockIdx.x * 256 + threadIdx.x;   // 1024 bc * 314 chunks
    int bc = ch / 314;
    int cp = ch - bc * 314;
    int p0 = cp * 8;
    const float* xsrc = x + (size_t)bc * 2304;
    short8 v[9];
#pragma unroll
    for (int e = 0; e < 8; ++e) {
        int p = p0 + e;
        int hh = p / 50;
        int ww = p - hh * 50;
        float xv = (hh >= 1 && hh <= 48 && ww >= 1 && ww <= 48) ? xsrc[(hh - 1) * 48 + (ww - 1)] : 0.0f;
        float phi[9];
        compute_phi(xv, phi);
#pragma unroll
        for (int j = 0; j < 9; ++j) v[j][e] = (short)f2bf(phi[j]);
    }
    unsigned short* pdst = Phi + (size_t)bc * 9 * PLANE + p0;
#pragma unroll
    for (int j = 0; j < 9; ++j) *(short8*)(pdst + (size_t)j * PLANE) = v[j];
}

// Pass 0: pack weights in MFMA-fragment-contiguous order.
// Tile kt (16KB): [f=oc/16][ks=(k&63)>>5][lane=((k&31)>>3)*16+(oc&15)][e=k&7] bf16.
__global__ __launch_bounds__(256) void pack_kernel(const float* __restrict__ bw,
                                                   const float* __restrict__ sw,
                                                   const float* __restrict__ sc,
                                                   unsigned short* __restrict__ Wp) {
    int gtid = blockIdx.x * 256 + threadIdx.x;  // oc*576 + q ; 73728 total
    int oc = gtid / QDIM, q = gtid % QDIM;
    float base = bw[gtid];
    float scal = sc[gtid];
    unsigned char* wp8 = (unsigned char*)Wp;
    int kk = q & 63;
    int inner = (oc >> 4) * 2048 + (kk >> 5) * 1024
              + ((((kk >> 3) & 3) << 4) + (oc & 15)) * 16 + (kk & 7) * 2;
    int ktb = q >> 6;
    *(unsigned short*)(wp8 + (size_t)ktb * 16384 + inner) = f2bf(base);
#pragma unroll
    for (int g = 0; g < 8; ++g) {
        float v = sw[(size_t)gtid * 8 + g] * scal;
        *(unsigned short*)(wp8 + (size_t)((g + 1) * 9 + ktb) * 16384 + inner) = f2bf(v);
    }
}

#define MFMA_BF16 __builtin_amdgcn_mfma_f32_16x16x32_bf16

// GEMM: out[n][oc] = sum_k A[n][k]*W[k][oc].  M=36864, N=128, K=5184.
// BM=48, BN=128, BK=64; grid=768 = 3 blocks/CU. 4 waves = (wo oc-half) x (wk k-half).
// Deep pipeline (T3+T4): A ring-4 in LDS staged 3 ahead via global_load_lds; W in
// named registers triple-buffered 2 ahead; counted vmcnt (never 0 in main loop) +
// raw s_barrier; setprio around MFMA cluster (T5). K-halves reduced via LDS epilogue.
__global__ __launch_bounds__(256, 3) void gemm_kernel(const unsigned short* __restrict__ Phi,
                                                      const unsigned short* __restrict__ Wp,
                                                      float* __restrict__ out) {
    __shared__ __align__(16) unsigned char lds[24960]; // A ring 4x6K; epilogue f32 [2][48][65]
    int bid = blockIdx.x;
    int swzb = (bid & 7) * 96 + (bid >> 3);   // XCD-bijective (768 = 8*96)
    int m0 = swzb * 48;
    int tid = threadIdx.x;
    int lane = tid & 63;
    int wv = tid >> 6;
    int wo = wv & 1, wk = wv >> 1;
    int lo = lane & 15, hi = lane >> 4, l7 = lane & 7;

    // A staging: chunks 0..255 = rows 0..31 (all tids), chunks 256..383 = rows 32..47 (tid<128)
    int s8 = tid & 7;
    int rA = tid >> 3;
    int sxA = s8 ^ (rA & 7);
    int rB = (tid < 128) ? (32 + (tid >> 3)) : rA;
    int sxB = s8 ^ (rB & 7);

    size_t rowb[2];
    int rows[2] = {rA, rB};
#pragma unroll
    for (int i = 0; i < 2; ++i) {
        int n  = m0 + rows[i];
        int b  = n / 2304;
        int u  = n - b * 2304;
        int du = u >> 2;          // patches feature (c,kh,kw)
        int r  = u & 3;           // 576-chunk within reinterpreted row
        int c  = du / 9;
        int tap = du - c * 9;
        int kh = tap / 3, kw = tap - kh * 3;
        rowb[i] = ((size_t)(b * C_IN + c) * 9) * PLANE + (size_t)((r * 12 + kh) * 50 + kw);
    }

    auto stageA = [&](int slot, int kt) {
        int j  = kt / 9;
        int q0 = (kt - j * 9) << 6;
        unsigned char* pb = lds + slot * 6144;
        {
            int qs = q0 + sxA * 8;
            int hq = qs / 48, wq = qs - hq * 48;   // 16B chunk never crosses 48-wrap
            const unsigned short* src = Phi + rowb[0] + (size_t)j * PLANE + (size_t)(hq * 50 + wq);
            __builtin_amdgcn_global_load_lds((const __attribute__((address_space(1))) void*)src,
                                             (__attribute__((address_space(3))) void*)(pb + tid * 16), 16, 0, 0);
        }
        if (tid < 128) {
            int qs = q0 + sxB * 8;
            int hq = qs / 48, wq = qs - hq * 48;
            const unsigned short* src = Phi + rowb[1] + (size_t)j * PLANE + (size_t)(hq * 50 + wq);
            __builtin_amdgcn_global_load_lds((const __attribute__((address_space(1))) void*)src,
                                             (__attribute__((address_space(3))) void*)(pb + 4096 + tid * 16), 16, 0, 0);
        }
    };

    const unsigned char* wsrc = (const unsigned char*)Wp
                              + (size_t)wo * 8192 + (size_t)wk * 1024 + (size_t)lane * 16;

#define LOADW(W0, W1, W2, W3, KT) do {                                      \
        const unsigned char* s_ = wsrc + (size_t)(KT) * 16384;              \
        W0 = *(const short8*)(s_);                                          \
        W1 = *(const short8*)(s_ + 2048);                                   \
        W2 = *(const short8*)(s_ + 4096);                                   \
        W3 = *(const short8*)(s_ + 6144);                                   \
    } while (0)

#define COMPUTE(SLOT, W0, W1, W2, W3) do {                                  \
        const unsigned char* pb_ = lds + (SLOT) * 6144;                     \
        short8 a0_ = *(const short8*)(pb_ + arow0 + sxr);                   \
        short8 a1_ = *(const short8*)(pb_ + arow1 + sxr);                   \
        short8 a2_ = *(const short8*)(pb_ + arow2 + sxr);                   \
        __builtin_amdgcn_s_setprio(1);                                      \
        acc[0][0] = MFMA_BF16(a0_, W0, acc[0][0], 0, 0, 0);                 \
        acc[0][1] = MFMA_BF16(a0_, W1, acc[0][1], 0, 0, 0);                 \
        acc[0][2] = MFMA_BF16(a0_, W2, acc[0][2], 0, 0, 0);                 \
        acc[0][3] = MFMA_BF16(a0_, W3, acc[0][3], 0, 0, 0);                 \
        acc[1][0] = MFMA_BF16(a1_, W0, acc[1][0], 0, 0, 0);                 \
        acc[1][1] = MFMA_BF16(a1_, W1, acc[1][1], 0, 0, 0);                 \
        acc[1][2] = MFMA_BF16(a1_, W2, acc[1][2], 0, 0, 0);                 \
        acc[1][3] = MFMA_BF16(a1_, W3, acc[1][3], 0, 0, 0);                 \
        acc[2][0] = MFMA_BF16(a2_, W0, acc[2][0], 0, 0, 0);                 \
        acc[2][1] = MFMA_BF16(a2_, W1, acc[2][1], 0, 0, 0);                 \
        acc[2][2] = MFMA_BF16(a2_, W2, acc[2][2], 0, 0, 0);                 \
        acc[2][3] = MFMA_BF16(a2_, W3, acc[2][3], 0, 0, 0);                 \
        __builtin_amdgcn_s_setprio(0);                                      \
    } while (0)

// Counted waits: waves 0/1 issue 2 stage ops/iter, waves 2/3 issue 1; each iter also
// issues 4 W-loads. vmcnt(6|5) keeps only the previous iteration's issues in flight.
#define WAITV(N01, N23) do {                                                \
        if (wv < 2) asm volatile("s_waitcnt vmcnt(" #N01 ")");              \
        else        asm volatile("s_waitcnt vmcnt(" #N23 ")");              \
    } while (0)

#define ITER(KT, WC0,WC1,WC2,WC3, WN0,WN1,WN2,WN3, DOSTAGE, DOLOADW, N01, N23) do { \
        WAITV(N01, N23);                                                    \
        __builtin_amdgcn_s_barrier();                                       \
        if (DOSTAGE) stageA(((KT) + 3) & 3, (KT) + 3);                      \
        if (DOLOADW) LOADW(WN0, WN1, WN2, WN3, (KT) + 2);                   \
        COMPUTE((KT) & 3, WC0, WC1, WC2, WC3);                              \
    } while (0)

    floatx4 acc[3][4];
    floatx4 zz = {0.f, 0.f, 0.f, 0.f};
#pragma unroll
    for (int a = 0; a < 3; ++a)
#pragma unroll
        for (int b = 0; b < 4; ++b) acc[a][b] = zz;

    int sxr = ((wk * 4 + hi) ^ l7) << 4;   // swizzled chunk-slot byte offset in A rows
    int arow0 = (0 * 16 + lo) * 128;
    int arow1 = (1 * 16 + lo) * 128;
    int arow2 = (2 * 16 + lo) * 128;

    short8 u0, u1, u2, u3, v0, v1, v2, v3, t0, t1, t2, t3;

    // Prologue: stage 3 A-tiles, load 2 W-tiles.
    stageA(0, 0); stageA(1, 1); stageA(2, 2);
    LOADW(u0, u1, u2, u3, 0);
    LOADW(v0, v1, v2, v3, 1);

    // iter 0: one-time full drain (prologue ordering not relied upon).
    ITER(0, u0,u1,u2,u3, t0,t1,t2,t3, 1, 1, 0, 0);

    // Main: kt = 1..75, unroll 3 (W-buffer rotation v->u, t->v, u->t).
    for (int kt = 1; kt <= 73; kt += 3) {
        ITER(kt,     v0,v1,v2,v3, u0,u1,u2,u3, 1, 1, 6, 5);
        ITER(kt + 1, t0,t1,t2,t3, v0,v1,v2,v3, 1, 1, 6, 5);
        ITER(kt + 2, u0,u1,u2,u3, t0,t1,t2,t3, 1, 1, 6, 5);
    }
    // Peeled tail: 76..80 (stages end at 80; W ends at 80).
    ITER(76, v0,v1,v2,v3, u0,u1,u2,u3, 1, 1, 6, 5);
    ITER(77, t0,t1,t2,t3, v0,v1,v2,v3, 1, 1, 6, 5);
    ITER(78, u0,u1,u2,u3, t0,t1,t2,t3, 0, 1, 6, 5);
    ITER(79, v0,v1,v2,v3, u0,u1,u2,u3, 0, 0, 4, 4);
    ITER(80, t0,t1,t2,t3, u0,u1,u2,u3, 0, 0, 0, 0);

    __syncthreads();

    // Epilogue: reduce k-halves via LDS (f32 [2][48][65]), then store.
    float* red = (float*)lds;
    if (wk == 1) {
#pragma unroll
        for (int fm = 0; fm < 3; ++fm)
#pragma unroll
            for (int fo = 0; fo < 4; ++fo)
#pragma unroll
                for (int r = 0; r < 4; ++r)
                    red[(wo * 48 + fm * 16 + hi * 4 + r) * 65 + fo * 16 + lo] = acc[fm][fo][r];
    }
    __syncthreads();
    if (wk == 0) {
#pragma unroll
        for (int fm = 0; fm < 3; ++fm) {
#pragma unroll
            for (int fo = 0; fo < 4; ++fo) {
                int oc = wo * 64 + fo * 16 + lo;
#pragma unroll
                for (int r = 0; r < 4; ++r) {
                    int nrow = m0 + fm * 16 + hi * 4 + r;
                    out[(size_t)nrow * 128 + oc] =
                        acc[fm][fo][r] + red[(wo * 48 + fm * 16 + hi * 4 + r) * 65 + fo * 16 + lo];
                }
            }
        }
    }
#undef LOADW
#undef COMPUTE
#undef WAITV
#undef ITER
}

extern "C" void kernel_launch(void* const* d_in, const int* in_sizes, int n_in,
                              void* d_out, int out_size, void* d_ws, size_t ws_size,
                              hipStream_t stream) {
    const float* x  = (const float*)d_in[0];
    const float* bw = (const float*)d_in[1];
    const float* sw = (const float*)d_in[2];
    const float* sc = (const float*)d_in[3];
    float* out = (float*)d_out;

    unsigned short* Wp  = (unsigned short*)d_ws;                        // 81*16384 = 1.33 MB
    unsigned short* Phi = (unsigned short*)((char*)d_ws + 1572864);     // 1024*9*2512*2 = 46.3 MB

    pack_kernel<<<288, 256, 0, stream>>>(bw, sw, sc, Wp);
    phi_kernel<<<1256, 256, 0, stream>>>(x, Phi);
    gemm_kernel<<<M_TOT / 48, 256, 0, stream>>>(Phi, Wp, out);
}

// Round 6
// 144.505 us; speedup vs baseline: 1.7056x; 1.0375x over previous
//
#include <hip/hip_runtime.h>
#include <hip/hip_bf16.h>

#define B_N    16
#define C_IN   64
#define QDIM   576
#define OC     128
#define M_TOT  36864
#define PLANE  2512   // 50*50 = 2500 padded to multiple of 8 for 16B stores
#define BM     96
#define NSTEP  41     // per k-half (kh=1's last step uses the zero W tile 81)

typedef __attribute__((ext_vector_type(8))) short short8;
typedef __attribute__((ext_vector_type(4))) float floatx4;

__device__ __forceinline__ unsigned short f2bf(float f) {
    union { float f; unsigned u; } v; v.f = f;
    unsigned r = (v.u + 0x7FFFu + ((v.u >> 16) & 1u)) >> 16;
    return (unsigned short)r;
}

// phi[0]=silu(x); phi[1..8]=cubic B-spline bases, uniform grid [-2.2..2.2], h=0.4.
__device__ __forceinline__ void compute_phi(float x, float* phi) {
    phi[0] = x * __builtin_amdgcn_rcpf(1.0f + __expf(-x));
    float t[12];
#pragma unroll
    for (int i = 0; i < 12; ++i) t[i] = 0.4f * (float)(i - 3) - 1.0f;
    float bb[11];
#pragma unroll
    for (int j = 0; j < 11; ++j) bb[j] = (x >= t[j] && x < t[j + 1]) ? 1.0f : 0.0f;
#pragma unroll
    for (int j = 0; j < 10; ++j)
        bb[j] = (x - t[j]) * 2.5f * bb[j] + (t[j + 2] - x) * 2.5f * bb[j + 1];
#pragma unroll
    for (int j = 0; j < 9; ++j)
        bb[j] = (x - t[j]) * 1.25f * bb[j] + (t[j + 3] - x) * 1.25f * bb[j + 1];
#pragma unroll
    for (int j = 0; j < 8; ++j)
        bb[j] = (x - t[j]) * (2.5f / 3.0f) * bb[j] + (t[j + 4] - x) * (2.5f / 3.0f) * bb[j + 1];
#pragma unroll
    for (int g = 0; g < 8; ++g) phi[1 + g] = bb[g];
}

// Fused prep: blocks 0..287 = weight pack (+ zero W tile 81); blocks 288.. = phi.
// Wp tile kt (16KB): addr = kt*16384 + wo*4096 + ks*2048 + fo*1024 + (hi8*16+lo)*16 + e*2
//   where oc = wo*32+fo*16+lo, kk = ks*32+hi8*8+e.  Lane fragment = contiguous 16B.
__global__ __launch_bounds__(256) void prep_kernel(const float* __restrict__ x,
                                                   const float* __restrict__ bw,
                                                   const float* __restrict__ sw,
                                                   const float* __restrict__ sc,
                                                   unsigned short* __restrict__ Wp,
                                                   unsigned short* __restrict__ Phi) {
    int bid = blockIdx.x;
    if (bid < 288) {
        int gtid = bid * 256 + threadIdx.x;      // oc*576 + q ; 73728 total
        if (gtid < 2048) {                        // zero W tile 81 (16KB, 8B/thread)
            *(unsigned long long*)((unsigned char*)Wp + 81 * 16384 + gtid * 8) = 0ull;
        }
        int oc = gtid / QDIM, q = gtid - oc * QDIM;
        float base = bw[gtid];
        float scal = sc[gtid];
        unsigned char* wp8 = (unsigned char*)Wp;
        int kk = q & 63;
        int wo = oc >> 5, fo = (oc >> 4) & 1, lo = oc & 15;
        int ks = kk >> 5, hi8 = (kk >> 3) & 3, e = kk & 7;
        int inner = wo * 4096 + ks * 2048 + fo * 1024 + (hi8 * 16 + lo) * 16 + e * 2;
        int ktb = q >> 6;
        *(unsigned short*)(wp8 + (size_t)ktb * 16384 + inner) = f2bf(base);
#pragma unroll
        for (int g = 0; g < 8; ++g) {
            float v = sw[(size_t)gtid * 8 + g] * scal;
            *(unsigned short*)(wp8 + (size_t)((g + 1) * 9 + ktb) * 16384 + inner) = f2bf(v);
        }
    } else {
        int ch = (bid - 288) * 256 + threadIdx.x;  // 1024 bc * 314 chunks
        int bc = ch / 314;
        int cp = ch - bc * 314;
        int p0 = cp * 8;
        const float* xsrc = x + (size_t)bc * 2304;
        short8 v[9];
#pragma unroll
        for (int e = 0; e < 8; ++e) {
            int p = p0 + e;
            int hh = p / 50;
            int ww = p - hh * 50;
            float xv = (hh >= 1 && hh <= 48 && ww >= 1 && ww <= 48) ? xsrc[(hh - 1) * 48 + (ww - 1)] : 0.0f;
            float phi[9];
            compute_phi(xv, phi);
#pragma unroll
            for (int j = 0; j < 9; ++j) v[j][e] = (short)f2bf(phi[j]);
        }
        unsigned short* pdst = Phi + (size_t)bc * 9 * PLANE + p0;
#pragma unroll
        for (int j = 0; j < 9; ++j) *(short8*)(pdst + (size_t)j * PLANE) = v[j];
    }
}

#define MFMA_BF16 __builtin_amdgcn_mfma_f32_16x16x32_bf16

// GEMM split-K x2: out[n][oc] = sum_k A[n][k]*W[k][oc]. M=36864, N=128, K=5184.
// BM=96, BN=128, BK=64; grid = 384 M-tiles x 2 k-halves = 768 = 3 blocks/CU.
// 4 waves by oc-quarter: wave = 96m x 32oc x BK, acc[6][2]. W -> named regs (dbuf),
// A -> LDS dbuf 12KB/step. kh=0 -> d_out, kh=1 -> partial; reduce kernel adds.
__global__ __launch_bounds__(256, 3) void gemm_kernel(const unsigned short* __restrict__ Phi,
                                                      const unsigned short* __restrict__ Wp,
                                                      float* __restrict__ out,
                                                      float* __restrict__ partial) {
    __shared__ __align__(16) unsigned char lds[24576]; // A dbuf 2x12KB
    int bid = blockIdx.x;
    int swz = (bid & 7) * 96 + (bid >> 3);   // XCD-bijective (768 = 8*96)
    int tile = swz >> 1, kh = swz & 1;
    int m0 = tile * BM;
    int kt0 = kh * NSTEP;                     // 0 or 41
    int tid = threadIdx.x;
    int lane = tid & 63;
    int wo = tid >> 6;                        // oc-quarter
    int lo = lane & 15, hi = lane >> 4, l7 = lane & 7;

    // A staging: 96 rows x 8 chunks = 768 chunks; thread stages rows r, r+32, r+64.
    int s8 = tid & 7;
    int r0 = tid >> 3;
    int sx = s8 ^ (r0 & 7);                   // same for all three rows (r&7 equal)
    size_t rowb[3];
#pragma unroll
    for (int i = 0; i < 3; ++i) {
        int n  = m0 + r0 + 32 * i;
        int b  = n / 2304;
        int u  = n - b * 2304;
        int du = u >> 2;                      // patches feature (c,kh,kw)
        int rr = u & 3;                       // 576-chunk within reinterpreted row
        int c  = du / 9;
        int tap = du - c * 9;
        int th = tap / 3, tw = tap - th * 3;
        rowb[i] = ((size_t)(b * C_IN + c) * 9) * PLANE + (size_t)((rr * 12 + th) * 50 + tw);
    }

    auto stageA = [&](int sel, int kt) {
        kt = min(kt, 80);                     // zero-W step reads kt=80's A (finite, x0)
        int j  = kt / 9;
        int q0 = (kt - j * 9) << 6;
        int qs = q0 + sx * 8;
        int hq = qs / 48, wq = qs - hq * 48;  // 16B chunk never crosses 48-wrap
        size_t delta = (size_t)j * PLANE + (size_t)(hq * 50 + wq);
        unsigned char* pb = lds + sel * 12288;
#pragma unroll
        for (int i = 0; i < 3; ++i) {
            const unsigned short* src = Phi + rowb[i] + delta;
            __builtin_amdgcn_global_load_lds((const __attribute__((address_space(1))) void*)src,
                                             (__attribute__((address_space(3))) void*)(pb + i * 4096 + tid * 16), 16, 0, 0);
        }
    };

    const unsigned char* wsrc = (const unsigned char*)Wp + (size_t)wo * 4096 + (size_t)lane * 16;

#define LOADW(W00, W01, W10, W11, KT) do {                                  \
        const unsigned char* s_ = wsrc + (size_t)(KT) * 16384;              \
        W00 = *(const short8*)(s_);                                         \
        W01 = *(const short8*)(s_ + 1024);                                  \
        W10 = *(const short8*)(s_ + 2048);                                  \
        W11 = *(const short8*)(s_ + 3072);                                  \
    } while (0)

#define HALF(PB, SXR, WA, WB) do {                                          \
        short8 a0_ = *(const short8*)((PB) + ar0 + (SXR));                  \
        short8 a1_ = *(const short8*)((PB) + ar1 + (SXR));                  \
        short8 a2_ = *(const short8*)((PB) + ar2 + (SXR));                  \
        short8 a3_ = *(const short8*)((PB) + ar3 + (SXR));                  \
        short8 a4_ = *(const short8*)((PB) + ar4 + (SXR));                  \
        short8 a5_ = *(const short8*)((PB) + ar5 + (SXR));                  \
        __builtin_amdgcn_s_setprio(1);                                      \
        acc[0][0] = MFMA_BF16(a0_, WA, acc[0][0], 0, 0, 0);                 \
        acc[0][1] = MFMA_BF16(a0_, WB, acc[0][1], 0, 0, 0);                 \
        acc[1][0] = MFMA_BF16(a1_, WA, acc[1][0], 0, 0, 0);                 \
        acc[1][1] = MFMA_BF16(a1_, WB, acc[1][1], 0, 0, 0);                 \
        acc[2][0] = MFMA_BF16(a2_, WA, acc[2][0], 0, 0, 0);                 \
        acc[2][1] = MFMA_BF16(a2_, WB, acc[2][1], 0, 0, 0);                 \
        acc[3][0] = MFMA_BF16(a3_, WA, acc[3][0], 0, 0, 0);                 \
        acc[3][1] = MFMA_BF16(a3_, WB, acc[3][1], 0, 0, 0);                 \
        acc[4][0] = MFMA_BF16(a4_, WA, acc[4][0], 0, 0, 0);                 \
        acc[4][1] = MFMA_BF16(a4_, WB, acc[4][1], 0, 0, 0);                 \
        acc[5][0] = MFMA_BF16(a5_, WA, acc[5][0], 0, 0, 0);                 \
        acc[5][1] = MFMA_BF16(a5_, WB, acc[5][1], 0, 0, 0);                 \
        __builtin_amdgcn_s_setprio(0);                                      \
    } while (0)

#define COMPUTE(SEL, W00, W01, W10, W11) do {                               \
        const unsigned char* pb_ = lds + (SEL) * 12288;                     \
        HALF(pb_, sxr0, W00, W01);                                          \
        HALF(pb_, sxr1, W10, W11);                                          \
    } while (0)

    floatx4 acc[6][2];
    floatx4 zz = {0.f, 0.f, 0.f, 0.f};
#pragma unroll
    for (int a = 0; a < 6; ++a) { acc[a][0] = zz; acc[a][1] = zz; }

    int sxr0 = (hi ^ l7) << 4;
    int sxr1 = ((4 + hi) ^ l7) << 4;
    int ar0 = (0 * 16 + lo) * 128, ar1 = (1 * 16 + lo) * 128, ar2 = (2 * 16 + lo) * 128;
    int ar3 = (3 * 16 + lo) * 128, ar4 = (4 * 16 + lo) * 128, ar5 = (5 * 16 + lo) * 128;

    short8 u00, u01, u10, u11, v00, v01, v10, v11;
    stageA(0, kt0);
    LOADW(u00, u01, u10, u11, kt0);
    __syncthreads();
    for (int t = 0; t < NSTEP - 1; t += 2) {
        stageA(1, kt0 + t + 1);
        LOADW(v00, v01, v10, v11, kt0 + t + 1);
        COMPUTE(0, u00, u01, u10, u11);
        __syncthreads();
        stageA(0, kt0 + t + 2);
        LOADW(u00, u01, u10, u11, kt0 + t + 2);
        COMPUTE(1, v00, v01, v10, v11);
        __syncthreads();
    }
    COMPUTE(0, u00, u01, u10, u11);           // step NSTEP-1

    // Store: kh=0 -> out, kh=1 -> partial (summed by reduce kernel).
    float* dst = kh ? partial : out;
#pragma unroll
    for (int fm = 0; fm < 6; ++fm) {
#pragma unroll
        for (int fo = 0; fo < 2; ++fo) {
            int oc = wo * 32 + fo * 16 + lo;
            int n0 = m0 + fm * 16 + hi * 4;
            float* op = dst + (size_t)n0 * 128 + oc;
#pragma unroll
            for (int r = 0; r < 4; ++r)
                op[(size_t)r * 128] = acc[fm][fo][r];
        }
    }
#undef LOADW
#undef HALF
#undef COMPUTE
}

// out += partial, float4 x2 per thread. 4,718,592 f32 = 1,179,648 float4.
__global__ __launch_bounds__(256) void reduce_kernel(const floatx4* __restrict__ p,
                                                     floatx4* __restrict__ o) {
    int i = blockIdx.x * 256 + threadIdx.x;   // 589,824 threads, 2 elements each
    floatx4 a0 = o[i], b0 = p[i];
    floatx4 a1 = o[i + 589824], b1 = p[i + 589824];
    o[i] = a0 + b0;
    o[i + 589824] = a1 + b1;
}

extern "C" void kernel_launch(void* const* d_in, const int* in_sizes, int n_in,
                              void* d_out, int out_size, void* d_ws, size_t ws_size,
                              hipStream_t stream) {
    const float* x  = (const float*)d_in[0];
    const float* bw = (const float*)d_in[1];
    const float* sw = (const float*)d_in[2];
    const float* sc = (const float*)d_in[3];
    float* out = (float*)d_out;

    unsigned short* Wp   = (unsigned short*)d_ws;                         // 82*16KB = 1.34 MB
    unsigned short* Phi  = (unsigned short*)((char*)d_ws + 1572864);      // 46.3 MB
    float*          part = (float*)((char*)d_ws + 50331648);              // 18.9 MB @ 48MiB

    prep_kernel<<<1544, 256, 0, stream>>>(x, bw, sw, sc, Wp, Phi);
    gemm_kernel<<<768, 256, 0, stream>>>(Phi, Wp, out, part);
    reduce_kernel<<<2304, 256, 0, stream>>>((const floatx4*)part, (floatx4*)out);
}